// Round 1
// baseline (4384.826 us; speedup 1.0000x reference)
//
#include <hip/hip_runtime.h>

// CIN (xDeepFM): B=512, F0=40, D=32, sizes=[200,200,200]
// h_next[b,n,d] = sum_{i<40, j<Fi} x0[b,i,d] * h[b,j,d] * W[i*Fi+j, n]
// out[b, l*200+n] = sum_d h_{l+1}[b,n,d]

#define CIN_B 512
#define CIN_F0 40
#define CIN_D 32
#define CIN_S 200

// One block per b. Threads: 256 = 32 d-lanes x 8 n-groups (25 n each).
// LDS: x0 and h staged transposed [d][field]; W staged in KT-row tiles.
template <int FI>
__global__ __launch_bounds__(256) void cin_layer(const float* __restrict__ x0,
                                                 const float* __restrict__ h,
                                                 const float* __restrict__ W,
                                                 float* __restrict__ h_next) {
    constexpr int K = CIN_F0 * FI;   // 1600 or 8000
    constexpr int KT = 16;           // k-tile rows staged per chunk (divides both K)

    __shared__ float Ax[CIN_D * CIN_F0];  // [d][i]
    __shared__ float Hx[CIN_D * FI];      // [d][j]
    __shared__ float Wt[KT * CIN_S];      // [kk][n]

    const int b = blockIdx.x;
    const int t = threadIdx.x;
    const int d = t >> 3;        // 0..31
    const int ng = t & 7;        // 0..7
    const int n0 = ng * 25;      // 25 consecutive n per thread

    // stage x0[b] transposed: Ax[d][i]
    for (int e = t; e < CIN_F0 * CIN_D; e += 256) {
        int i = e >> 5, dd = e & 31;
        Ax[dd * CIN_F0 + i] = x0[(b * CIN_F0 + i) * CIN_D + dd];
    }
    // stage h[b] transposed: Hx[d][j]
    for (int e = t; e < FI * CIN_D; e += 256) {
        int j = e >> 5, dd = e & 31;
        Hx[dd * FI + j] = h[(b * FI + j) * CIN_D + dd];
    }

    float acc[25];
#pragma unroll
    for (int m = 0; m < 25; ++m) acc[m] = 0.f;

    for (int k0 = 0; k0 < K; k0 += KT) {
        __syncthreads();
        // stage W[k0:k0+KT, :] (contiguous KT*200 floats), vectorized
        const float4* Wg = (const float4*)(W + k0 * CIN_S);
        float4* Wl = (float4*)Wt;
        for (int e = t; e < KT * CIN_S / 4; e += 256) Wl[e] = Wg[e];
        __syncthreads();

#pragma unroll
        for (int kk = 0; kk < KT; ++kk) {
            const int k = k0 + kk;
            const int i = k / FI;      // compile-time-const divisor -> magic mul
            const int j = k % FI;
            const float z = Ax[d * CIN_F0 + i] * Hx[d * FI + j];
            const float* wr = &Wt[kk * CIN_S + n0];
#pragma unroll
            for (int m = 0; m < 25; ++m) acc[m] = fmaf(z, wr[m], acc[m]);
        }
    }

    float* hw = h_next + (b * CIN_S + n0) * CIN_D + d;
#pragma unroll
    for (int m = 0; m < 25; ++m) hw[m * CIN_D] = acc[m];
}

// out[b, p] = sum_d h_layer[b, p%200, d], layer = p/200
__global__ __launch_bounds__(256) void cin_reduce(const float* __restrict__ h1,
                                                  const float* __restrict__ h2,
                                                  const float* __restrict__ h3,
                                                  float* __restrict__ out) {
    const int tid = blockIdx.x * blockDim.x + threadIdx.x;
    if (tid >= CIN_B * 3 * CIN_S) return;
    const int b = tid / (3 * CIN_S);
    const int p = tid % (3 * CIN_S);
    const float* src = (p < CIN_S) ? h1 : ((p < 2 * CIN_S) ? h2 : h3);
    const int n = p % CIN_S;
    const float4* v = (const float4*)(src + (b * CIN_S + n) * CIN_D);
    float s = 0.f;
#pragma unroll
    for (int q = 0; q < CIN_D / 4; ++q) {
        float4 x = v[q];
        s += (x.x + x.y) + (x.z + x.w);
    }
    out[tid] = s;  // tid == b*600 + p
}

extern "C" void kernel_launch(void* const* d_in, const int* in_sizes, int n_in,
                              void* d_out, int out_size, void* d_ws, size_t ws_size,
                              hipStream_t stream) {
    const float* inputs = (const float*)d_in[0];
    const float* W0 = (const float*)d_in[1];
    const float* W1 = (const float*)d_in[2];
    const float* W2 = (const float*)d_in[3];
    float* out = (float*)d_out;

    const size_t hsz = (size_t)CIN_B * CIN_S * CIN_D;  // 3.276M floats each
    float* h1 = (float*)d_ws;
    float* h2 = h1 + hsz;
    float* h3 = h2 + hsz;

    cin_layer<CIN_F0><<<CIN_B, 256, 0, stream>>>(inputs, inputs, W0, h1);
    cin_layer<CIN_S><<<CIN_B, 256, 0, stream>>>(inputs, h1, W1, h2);
    cin_layer<CIN_S><<<CIN_B, 256, 0, stream>>>(inputs, h2, W2, h3);

    const int nout = CIN_B * 3 * CIN_S;  // 307200
    cin_reduce<<<(nout + 255) / 256, 256, 0, stream>>>(h1, h2, h3, out);
}

// Round 2
// 981.804 us; speedup vs baseline: 4.4661x; 4.4661x over previous
//
#include <hip/hip_runtime.h>

#define CIN_B 512
#define CIN_F0 40
#define CIN_D 32
#define CIN_S 200
#define NPAD 208      // padded n rows in Wt (200..207 zero)
#define HROW 224      // padded n cols in H buffers

typedef short bf16x8 __attribute__((ext_vector_type(8)));
typedef float floatx4 __attribute__((ext_vector_type(4)));

__device__ __forceinline__ float b2f(unsigned short u) {
    union { unsigned int i; float f; } c; c.i = ((unsigned int)u) << 16; return c.f;
}
__device__ __forceinline__ unsigned short f2b(float f) {
    union { float f; unsigned int i; } c; c.f = f;
    unsigned int i = c.i;
    unsigned int r = (i + 0x7fffu + ((i >> 16) & 1u)) >> 16;  // RNE
    return (unsigned short)r;
}

// Wt[n][i*FIP + j] = bf16(W[(i*FI+j)*200 + n]); zero-pad n>=200 and j>=FI.
template <int FI, int FIP>
__global__ __launch_bounds__(256) void prep_w(const float* __restrict__ W,
                                              unsigned short* __restrict__ Wt) {
    constexpr int Kp = CIN_F0 * FIP;
    int e = blockIdx.x * 256 + threadIdx.x;
    if (e >= NPAD * Kp) return;
    int n = e % NPAD;           // fastest -> coalesced source reads
    int kp = e / NPAD;
    int i = kp / FIP;
    int j = kp - i * FIP;
    unsigned short v = 0;
    if (n < CIN_S && j < FI) v = f2b(W[(size_t)(i * FI + j) * CIN_S + n]);
    Wt[(size_t)n * Kp + kp] = v;
}

// X0p[b][d][i] = bf16(x0[b][i][d]), i padded to 64 with zeros.
__global__ __launch_bounds__(256) void prep_x(const float* __restrict__ X,
                                              unsigned short* __restrict__ X0p) {
    int e = blockIdx.x * 256 + threadIdx.x;   // 512*2048 exact
    int b = e >> 11;
    int r = e & 2047;
    int i = r >> 5;      // 0..63
    int d = r & 31;
    unsigned short v = 0;
    if (i < CIN_F0) v = f2b(X[((size_t)b * CIN_F0 + i) * CIN_D + d]);
    X0p[((size_t)b << 11) + ((size_t)d << 6) + i] = v;
}

// Per b: h'[n,d] = sum_i x0[i,d] * (sum_j Wt[n][i*FIP+j] * h[j,d])
// Block: 4 b, 8 waves = (dt in {0,1}) x (nh in 0..3); wave does 4 n-tiles x 4 b.
// MFMA 16x16x32_bf16: A[m=lane&15][k=quad*8+e] = Wt rows (m=n), 8 consecutive kp;
// B[k=quad*8+e][n=lane&15] = h[d][j], 8 consecutive j; C/D col=lane&15 (d), row=quad*4+reg (n).
template <int FIP, int CPI>   // CPI = FIP/32
__global__ __launch_bounds__(512, 1)
void cin_mfma(const unsigned short* __restrict__ Hin,
              const unsigned short* __restrict__ X0g,
              const unsigned short* __restrict__ Wt,
              unsigned short* __restrict__ Hout) {
    constexpr int Kp = CIN_F0 * FIP;
    __shared__ __align__(16) unsigned short HtS[4][CIN_D][FIP];
    const int tid = threadIdx.x;
    const int b0 = blockIdx.x * 4;

    // stage h planes [32][FIP] bf16 for 4 b (coalesced uint4)
    {
        constexpr int U = CIN_D * FIP / 8;           // uint4 per plane
        const uint4* src = (const uint4*)Hin + (size_t)b0 * U;
        for (int g = tid; g < 4 * U; g += 512) {
            int bb = g / U, idx = g % U;
            int r = idx / (FIP / 8), c = idx % (FIP / 8);
            *(uint4*)&HtS[bb][r][c * 8] = src[g];
        }
    }
    __syncthreads();

    const int lane = tid & 63, wave = tid >> 6;
    const int dt = wave & 1, nh = wave >> 2 ? (wave >> 1) & 3 : (wave >> 1) & 3; // nh = (wave>>1)
    const int nh2 = wave >> 1;
    const int l16 = lane & 15, quad = lane >> 4;
    const int d = dt * 16 + l16;

    floatx4 acc[4][4];
#pragma unroll
    for (int b = 0; b < 4; ++b)
#pragma unroll
        for (int t = 0; t < 4; ++t) acc[b][t] = (floatx4){0.f, 0.f, 0.f, 0.f};

    const unsigned short* Abase[4];
#pragma unroll
    for (int t = 0; t < 4; ++t) {
        int n = (nh2 * 3 + t) * 16 + l16;   // tiles 0-3,3-6,6-9,9-12 (dups benign)
        Abase[t] = Wt + (size_t)n * Kp + quad * 8;
    }
    const floatx4 zero4 = (floatx4){0.f, 0.f, 0.f, 0.f};

#pragma unroll 1
    for (int i = 0; i < CIN_F0; ++i) {
        // prefetch x0 scalars for the fold (L1-resident after first i)
        unsigned short xu[4];
#pragma unroll
        for (int b = 0; b < 4; ++b)
            xu[b] = X0g[((size_t)(b0 + b) << 11) + (d << 6) + i];

        floatx4 P[4][4];
#pragma unroll
        for (int jc = 0; jc < CPI; ++jc) {
            const int c32 = (i * CPI + jc) * 32;
            bf16x8 Af[4];
#pragma unroll
            for (int t = 0; t < 4; ++t) Af[t] = *(const bf16x8*)(Abase[t] + c32);
            bf16x8 Bf[4];
#pragma unroll
            for (int b = 0; b < 4; ++b)
                Bf[b] = *(const bf16x8*)&HtS[b][d][jc * 32 + quad * 8];
#pragma unroll
            for (int b = 0; b < 4; ++b)
#pragma unroll
                for (int t = 0; t < 4; ++t)
                    P[b][t] = __builtin_amdgcn_mfma_f32_16x16x32_bf16(
                        Af[t], Bf[b], (jc == 0) ? zero4 : P[b][t], 0, 0, 0);
        }
#pragma unroll
        for (int b = 0; b < 4; ++b) {
            const float xf = b2f(xu[b]);
#pragma unroll
            for (int t = 0; t < 4; ++t) acc[b][t] += xf * P[b][t];
        }
    }

    // epilogue: C[n][d] -> Hout[b][d][n] bf16
#pragma unroll
    for (int b = 0; b < 4; ++b) {
        unsigned short* orow = Hout + (((size_t)(b0 + b) * CIN_D) + d) * HROW;
#pragma unroll
        for (int t = 0; t < 4; ++t) {
            int n = (nh2 * 3 + t) * 16 + quad * 4;
            ushort4 pk;
            pk.x = f2b(acc[b][t].x);
            pk.y = f2b(acc[b][t].y);
            pk.z = f2b(acc[b][t].z);
            pk.w = f2b(acc[b][t].w);
            *(ushort4*)&orow[n] = pk;   // tile overlap rewrites identical bytes
        }
    }
    // zero pad n = 208..223 (4 b x 32 d rows, 32B each)
    if (tid < 256) {
        int bb = tid >> 6, dd = (tid >> 1) & 31, hf = tid & 1;
        uint4 z = {0, 0, 0, 0};
        *(uint4*)&Hout[(((size_t)(b0 + bb) * CIN_D) + dd) * HROW + NPAD + hf * 8] = z;
    }
}

// out[b, l*200+n] = sum_d H_l[b][d][n]
__global__ __launch_bounds__(256) void cin_reduce(const unsigned short* __restrict__ H1,
                                                  const unsigned short* __restrict__ H2,
                                                  const unsigned short* __restrict__ H3,
                                                  float* __restrict__ out) {
    __shared__ __align__(16) unsigned short L[CIN_D][HROW];
    const int bid = blockIdx.x;            // 0..1535
    const int b = bid / 3, l = bid % 3;
    const unsigned short* H = (l == 0 ? H1 : (l == 1 ? H2 : H3)) + (size_t)b * CIN_D * HROW;
    const uint4* src = (const uint4*)H;
    for (int g = threadIdx.x; g < CIN_D * HROW / 8; g += 256) {
        int r = g / (HROW / 8), c = g % (HROW / 8);
        *(uint4*)&L[r][c * 8] = src[g];
    }
    __syncthreads();
    int n = threadIdx.x;
    if (n < CIN_S) {
        float s = 0.f;
#pragma unroll
        for (int dd = 0; dd < CIN_D; ++dd) s += b2f(L[dd][n]);
        out[(size_t)b * (3 * CIN_S) + l * CIN_S + n] = s;
    }
}

extern "C" void kernel_launch(void* const* d_in, const int* in_sizes, int n_in,
                              void* d_out, int out_size, void* d_ws, size_t ws_size,
                              hipStream_t stream) {
    const float* X  = (const float*)d_in[0];
    const float* W0 = (const float*)d_in[1];
    const float* W1 = (const float*)d_in[2];
    const float* W2 = (const float*)d_in[3];
    float* out = (float*)d_out;

    unsigned short* Wt0 = (unsigned short*)d_ws;                       // 208*2560
    unsigned short* Wt1 = Wt0 + (size_t)NPAD * (CIN_F0 * 64);          // 208*8960
    unsigned short* Wt2 = Wt1 + (size_t)NPAD * (CIN_F0 * 224);
    unsigned short* X0p = Wt2 + (size_t)NPAD * (CIN_F0 * 224);         // 512*2048
    unsigned short* H1  = X0p + (size_t)CIN_B * 2048;                  // 512*32*224 each
    unsigned short* H2  = H1 + (size_t)CIN_B * CIN_D * HROW;
    unsigned short* H3  = H2 + (size_t)CIN_B * CIN_D * HROW;
    // total ws use: ~32.6 MB (< previous round's proven 39.3 MB)

    prep_w<CIN_F0, 64><<<(NPAD * CIN_F0 * 64 + 255) / 256, 256, 0, stream>>>(W0, Wt0);
    prep_w<CIN_S, 224><<<(NPAD * CIN_F0 * 224 + 255) / 256, 256, 0, stream>>>(W1, Wt1);
    prep_w<CIN_S, 224><<<(NPAD * CIN_F0 * 224 + 255) / 256, 256, 0, stream>>>(W2, Wt2);
    prep_x<<<(CIN_B * 2048) / 256, 256, 0, stream>>>(X, X0p);

    cin_mfma<64, 2><<<CIN_B / 4, 512, 0, stream>>>(X0p, X0p, Wt0, H1);
    cin_mfma<224, 7><<<CIN_B / 4, 512, 0, stream>>>(H1, X0p, Wt1, H2);
    cin_mfma<224, 7><<<CIN_B / 4, 512, 0, stream>>>(H2, X0p, Wt2, H3);

    cin_reduce<<<CIN_B * 3, 256, 0, stream>>>(H1, H2, H3, out);
}

// Round 3
// 900.133 us; speedup vs baseline: 4.8713x; 1.0907x over previous
//
#include <hip/hip_runtime.h>

#define CIN_B 512
#define CIN_F0 40
#define CIN_D 32
#define CIN_S 200
#define NPAD 208      // padded n rows in Wt (200..207 zero)
#define HROW 224      // padded n cols in H buffers

typedef short bf16x8 __attribute__((ext_vector_type(8)));
typedef float floatx4 __attribute__((ext_vector_type(4)));

__device__ __forceinline__ float b2f(unsigned short u) {
    union { unsigned int i; float f; } c; c.i = ((unsigned int)u) << 16; return c.f;
}
__device__ __forceinline__ unsigned short f2b(float f) {
    union { float f; unsigned int i; } c; c.f = f;
    unsigned int i = c.i;
    unsigned int r = (i + 0x7fffu + ((i >> 16) & 1u)) >> 16;  // RNE
    return (unsigned short)r;
}

// Wt[n][i*FIP + j] = bf16(W[(i*FI+j)*200 + n]); zero-pad n>=200 and j>=FI.
template <int FI, int FIP>
__global__ __launch_bounds__(256) void prep_w(const float* __restrict__ W,
                                              unsigned short* __restrict__ Wt) {
    constexpr int Kp = CIN_F0 * FIP;
    int e = blockIdx.x * 256 + threadIdx.x;
    if (e >= NPAD * Kp) return;
    int n = e % NPAD;           // fastest -> coalesced source reads
    int kp = e / NPAD;
    int i = kp / FIP;
    int j = kp - i * FIP;
    unsigned short v = 0;
    if (n < CIN_S && j < FI) v = f2b(W[(size_t)(i * FI + j) * CIN_S + n]);
    Wt[(size_t)n * Kp + kp] = v;
}

// X0p[b][d][i] = bf16(x0[b][i][d]), i padded to 64 with zeros.
__global__ __launch_bounds__(256) void prep_x(const float* __restrict__ X,
                                              unsigned short* __restrict__ X0p) {
    int e = blockIdx.x * 256 + threadIdx.x;   // 512*2048 exact
    int b = e >> 11;
    int r = e & 2047;
    int i = r >> 5;      // 0..63
    int d = r & 31;
    unsigned short v = 0;
    if (i < CIN_F0) v = f2b(X[((size_t)b * CIN_F0 + i) * CIN_D + d]);
    X0p[((size_t)b << 11) + ((size_t)d << 6) + i] = v;
}

// Per b: h'[n,d] = sum_i x0[i,d] * (sum_j Wt[n][i*FIP+j] * h[j,d])
// Grid: 1024 blocks = 128 b-groups x 2 d-halves x 4 tile-groups.
// Block: 256 thr = 4 waves; wave = one 16-row n-tile x 4 b.
// MFMA 16x16x32_bf16: A[m=lane&15][k=quad*8+e] = Wt rows (m=n);
// B[k][n=lane&15] = h[d][j]; C/D col=lane&15 (d), row=quad*4+reg (n).
template <int FIP, int CPI>   // CPI = FIP/32
__global__ __launch_bounds__(256, 4)
void cin_mfma(const unsigned short* __restrict__ Hin,
              const unsigned short* __restrict__ X0g,
              const unsigned short* __restrict__ Wt,
              unsigned short* __restrict__ Hout) {
    constexpr int Kp = CIN_F0 * FIP;
    __shared__ __align__(16) unsigned short HtS[4][16][FIP];
    const int tid = threadIdx.x;
    const int bid = blockIdx.x;
    const int bg = bid >> 3;
    const int dt = (bid >> 2) & 1;
    const int th = bid & 3;
    const int b0 = bg * 4;

    // stage h half-planes: 4 b x 16 d (this dt half) x FIP, coalesced uint4
    {
        constexpr int U = 16 * FIP / 8;   // uint4 per half-plane
        for (int g = tid; g < 4 * U; g += 256) {
            int bb = g / U, idx = g - bb * U;
            int r = idx / (FIP / 8), c = idx - r * (FIP / 8);
            const uint4* src =
                (const uint4*)(Hin + ((size_t)(b0 + bb) * CIN_D + dt * 16 + r) * FIP);
            *(uint4*)&HtS[bb][r][c * 8] = src[c];
        }
    }
    __syncthreads();

    const int wave = tid >> 6;
    const int tcnt = th ? 3 : 4;
    if (wave >= tcnt) return;                 // idle waves exit after staging
    const int tile = th * 3 + (th ? 1 : 0) + wave;   // {0-3},{4-6},{7-9},{10-12}

    const int lane = tid & 63;
    const int l16 = lane & 15, quad = lane >> 4;
    const int d = dt * 16 + l16;

    const unsigned short* Ab = Wt + (size_t)(tile * 16 + l16) * Kp + quad * 8;
    const unsigned short* Xp = X0g + ((size_t)b0 << 11) + (d << 6);

    floatx4 acc[4];
#pragma unroll
    for (int b = 0; b < 4; ++b) acc[b] = (floatx4){0.f, 0.f, 0.f, 0.f};
    const floatx4 zero4 = (floatx4){0.f, 0.f, 0.f, 0.f};

#pragma unroll 1
    for (int i = 0; i < CIN_F0; ++i) {
        unsigned short xu[4];
#pragma unroll
        for (int b = 0; b < 4; ++b) xu[b] = Xp[(b << 11) + i];

        floatx4 P[4];
#pragma unroll
        for (int jc = 0; jc < CPI; ++jc) {
            const bf16x8 Af = *(const bf16x8*)(Ab + i * FIP + jc * 32);
#pragma unroll
            for (int b = 0; b < 4; ++b) {
                const bf16x8 Bf = *(const bf16x8*)&HtS[b][l16][jc * 32 + quad * 8];
                P[b] = __builtin_amdgcn_mfma_f32_16x16x32_bf16(
                    Af, Bf, (jc == 0) ? zero4 : P[b], 0, 0, 0);
            }
        }
#pragma unroll
        for (int b = 0; b < 4; ++b) acc[b] += b2f(xu[b]) * P[b];
    }

    // epilogue: C[n][d] -> Hout[b][d][n] bf16 (n = tile*16 + quad*4 .. +3)
#pragma unroll
    for (int b = 0; b < 4; ++b) {
        ushort4 pk;
        pk.x = f2b(acc[b].x);
        pk.y = f2b(acc[b].y);
        pk.z = f2b(acc[b].z);
        pk.w = f2b(acc[b].w);
        *(ushort4*)&Hout[((size_t)(b0 + b) * CIN_D + d) * HROW + tile * 16 + quad * 4] = pk;
    }
    // n pads 208..223 stay poison: next layer multiplies them by Wt zero cols
    // (j>=200) and reduce reads only n<200, so finite poison is harmless.
}

// out[b, l*200+n] = sum_d H_l[b][d][n]
__global__ __launch_bounds__(256) void cin_reduce(const unsigned short* __restrict__ H1,
                                                  const unsigned short* __restrict__ H2,
                                                  const unsigned short* __restrict__ H3,
                                                  float* __restrict__ out) {
    __shared__ __align__(16) unsigned short L[CIN_D][HROW];
    const int bid = blockIdx.x;            // 0..1535
    const int b = bid / 3, l = bid % 3;
    const unsigned short* H = (l == 0 ? H1 : (l == 1 ? H2 : H3)) + (size_t)b * CIN_D * HROW;
    const uint4* src = (const uint4*)H;
    for (int g = threadIdx.x; g < CIN_D * HROW / 8; g += 256) {
        int r = g / (HROW / 8), c = g % (HROW / 8);
        *(uint4*)&L[r][c * 8] = src[g];
    }
    __syncthreads();
    int n = threadIdx.x;
    if (n < CIN_S) {
        float s = 0.f;
#pragma unroll
        for (int dd = 0; dd < CIN_D; ++dd) s += b2f(L[dd][n]);
        out[(size_t)b * (3 * CIN_S) + l * CIN_S + n] = s;
    }
}

extern "C" void kernel_launch(void* const* d_in, const int* in_sizes, int n_in,
                              void* d_out, int out_size, void* d_ws, size_t ws_size,
                              hipStream_t stream) {
    const float* X  = (const float*)d_in[0];
    const float* W0 = (const float*)d_in[1];
    const float* W1 = (const float*)d_in[2];
    const float* W2 = (const float*)d_in[3];
    float* out = (float*)d_out;

    unsigned short* Wt0 = (unsigned short*)d_ws;                       // 208*2560
    unsigned short* Wt1 = Wt0 + (size_t)NPAD * (CIN_F0 * 64);          // 208*8960
    unsigned short* Wt2 = Wt1 + (size_t)NPAD * (CIN_F0 * 224);
    unsigned short* X0p = Wt2 + (size_t)NPAD * (CIN_F0 * 224);         // 512*2048
    unsigned short* H1  = X0p + (size_t)CIN_B * 2048;                  // 512*32*224 each
    unsigned short* H2  = H1 + (size_t)CIN_B * CIN_D * HROW;
    unsigned short* H3  = H2 + (size_t)CIN_B * CIN_D * HROW;
    // total ws use ~26.3 MB

    prep_w<CIN_F0, 64><<<(NPAD * CIN_F0 * 64 + 255) / 256, 256, 0, stream>>>(W0, Wt0);
    prep_w<CIN_S, 224><<<(NPAD * CIN_F0 * 224 + 255) / 256, 256, 0, stream>>>(W1, Wt1);
    prep_w<CIN_S, 224><<<(NPAD * CIN_F0 * 224 + 255) / 256, 256, 0, stream>>>(W2, Wt2);
    prep_x<<<(CIN_B * 2048) / 256, 256, 0, stream>>>(X, X0p);

    cin_mfma<64, 2><<<1024, 256, 0, stream>>>(X0p, X0p, Wt0, H1);
    cin_mfma<224, 7><<<1024, 256, 0, stream>>>(H1, X0p, Wt1, H2);
    cin_mfma<224, 7><<<1024, 256, 0, stream>>>(H2, X0p, Wt2, H3);

    cin_reduce<<<CIN_B * 3, 256, 0, stream>>>(H1, H2, H3, out);
}

// Round 4
// 366.928 us; speedup vs baseline: 11.9501x; 2.4532x over previous
//
#include <hip/hip_runtime.h>

#define CIN_B 512
#define CIN_F0 40
#define CIN_D 32
#define CIN_S 200

typedef short bf16x8 __attribute__((ext_vector_type(8)));
typedef float floatx16 __attribute__((ext_vector_type(16)));

__device__ __forceinline__ float bits2f(unsigned int u) {
    union { unsigned int i; float f; } c; c.i = u; return c.f;
}
__device__ __forceinline__ unsigned short f2b(float f) {
    union { float f; unsigned int i; } c; c.f = f;
    unsigned int i = c.i;
    return (unsigned short)((i + 0x7fffu + ((i >> 16) & 1u)) >> 16);  // RNE
}
__device__ __forceinline__ float b2f(unsigned short u) {
    return bits2f(((unsigned int)u) << 16);
}

// Wtk[kc][nn 0..255][kw 0..15] = bf16(W[(i*FI + kk*16+kw)*200 + nn]); kc = i*KCPI+kk.
// Zero-pad nn>=200 and j>=FI. One block per kc; coalesced W reads (nn = lane).
template <int FI, int KCPI>
__global__ __launch_bounds__(256) void prep_w(const float* __restrict__ W,
                                              unsigned short* __restrict__ Wtk) {
    const int kc = blockIdx.x;
    const int nn = threadIdx.x;
    const int i = kc / KCPI;
    const int kk = kc - i * KCPI;
    unsigned short v[16];
#pragma unroll
    for (int kw = 0; kw < 16; ++kw) {
        int j = kk * 16 + kw;
        float f = 0.f;
        if (j < FI && nn < CIN_S) f = W[(size_t)(i * FI + j) * CIN_S + nn];
        v[kw] = f2b(f);
    }
    uint4* dst = (uint4*)(Wtk + ((size_t)kc * 256 + nn) * 16);
    dst[0] = ((const uint4*)v)[0];
    dst[1] = ((const uint4*)v)[1];
}

// X0h[b][d][i(pad 48)] = bf16(x0[b][i][d])  (layer-1 "H" in [b][d][j] form)
// Xs[b][i][d] = fp32 x0 (scale source for all layers)
__global__ __launch_bounds__(256) void prep_x(const float* __restrict__ X,
                                              unsigned short* __restrict__ X0h,
                                              float* __restrict__ Xs) {
    int e = blockIdx.x * 256 + threadIdx.x;   // 512*40*32
    int d = e & 31;
    int rest = e >> 5;
    int i = rest % CIN_F0;
    int b = rest / CIN_F0;
    float v = X[e];
    Xs[e] = v;
    X0h[((size_t)b * CIN_D + d) * 48 + i] = f2b(v);
    if (e < CIN_B * CIN_D * 8) {     // zero pads i=40..47
        int q = e & 7, dd = (e >> 3) & 31, bb = e >> 8;
        X0h[((size_t)bb * CIN_D + dd) * 48 + 40 + q] = 0;
    }
}

// Layer: Hout[b][d][n] = sum_i sum_j Wt[n,(i,j)] * bf16(h[b][j][d]*x0[b][i][d])
// Block: b-pair, 512 thr = 8 waves = 4 tile-groups x 2 k-halves.
// Wave: 2 tiles x 2 b, acc = 4 x floatx16, direct accumulation (x0 folded into B).
// mfma_f32_32x32x16_bf16: A[m=lane&31][k=(lane>>5)*8+e] (m=n-row),
// B[k][col=lane&31] (col=d), C/D col=lane&31, row=(reg&3)+8*(reg>>2)+4*(lane>>5).
template <int KCPI, int RP, int JROW>
__global__ __launch_bounds__(512, 2)
void cin_layer(const unsigned short* __restrict__ Hin,   // [b][32][JROW] bf16
               const float* __restrict__ Xs,             // [b][40][32] fp32
               const unsigned short* __restrict__ Wtk,   // [kc][256][16] bf16
               unsigned short* __restrict__ Hout) {      // [b][32][224] bf16
    constexpr int CNT0 = (KCPI + 1) / 2;
    constexpr int HB = 2 * CIN_D * RP * 2;      // staged H bytes
    constexpr int BB = 2 * KCPI * 512 * 2;      // B' bytes
    constexpr int XB = 2 * CIN_F0 * CIN_D * 4;  // Xs bytes
    constexpr int SMB = (HB + BB + XB) > 32768 ? (HB + BB + XB) : 32768;
    __shared__ __align__(16) unsigned char SM[SMB];
    unsigned short* HtS = (unsigned short*)SM;
    unsigned short* Bp = (unsigned short*)(SM + HB);
    float* XsS = (float*)(SM + HB + BB);

    const int tid = threadIdx.x;
    const int b0 = blockIdx.x * 2;

    {   // stage H planes (insert row pad RP) + Xs
        constexpr int UPB = CIN_D * JROW / 8;
        for (int g = tid; g < 2 * UPB; g += 512) {
            int bb = g / UPB, idx = g - bb * UPB;
            int d = idx / (JROW / 8), c = idx - d * (JROW / 8);
            uint4 v = ((const uint4*)(Hin + (size_t)(b0 + bb) * CIN_D * JROW))[idx];
            *(uint4*)&HtS[(bb * CIN_D + d) * RP + c * 8] = v;
        }
        for (int g = tid; g < 2 * 320; g += 512) {
            int bb = g / 320, idx = g - bb * 320;
            float4 v = ((const float4*)(Xs + (size_t)(b0 + bb) * 1280))[idx];
            *(float4*)&XsS[bb * 1280 + idx * 4] = v;
        }
    }

    const int wave = tid >> 6, lane = tid & 63;
    const int tg = wave >> 1, kh = wave & 1;
    const int l32 = lane & 31, hl = lane >> 5;
    const int kk0 = kh ? CNT0 : 0;

    floatx16 acc[2][2];
#pragma unroll
    for (int ta = 0; ta < 2; ++ta)
#pragma unroll
        for (int bb = 0; bb < 2; ++bb)
#pragma unroll
            for (int r = 0; r < 16; ++r) acc[ta][bb][r] = 0.f;

    const unsigned short* Arow0 = Wtk + ((size_t)(tg * 64 + l32) * 16 + hl * 8);

    __syncthreads();

#pragma unroll 1
    for (int i = 0; i < CIN_F0; ++i) {
        // build B'[b][kk][hl][d][e] = bf16(h[j0+e][d] * x0[i][d])
        for (int g = tid; g < 2 * KCPI * 64; g += 512) {
            int bb = g / (KCPI * 64), r = g - bb * (KCPI * 64);
            int kk = r >> 6, h2 = (r >> 5) & 1, d = r & 31;
            int j0 = kk * 16 + h2 * 8;
            uint4 hv = *(const uint4*)&HtS[(bb * CIN_D + d) * RP + j0];
            float x0 = XsS[bb * 1280 + i * CIN_D + d];
            const unsigned int* hw = (const unsigned int*)&hv;
            unsigned int ov[4];
#pragma unroll
            for (int q = 0; q < 4; ++q) {
                unsigned int u = hw[q];
                float flo = bits2f(u << 16) * x0;
                float fhi = bits2f(u & 0xffff0000u) * x0;
                ov[q] = (unsigned int)f2b(flo) | ((unsigned int)f2b(fhi) << 16);
            }
            *(uint4*)&Bp[(bb * KCPI + kk) * 512 + h2 * 256 + d * 8] = *(const uint4*)ov;
        }
        __syncthreads();

#pragma unroll
        for (int q = 0; q < CNT0; ++q) {
            const int kk = kk0 + q;
            if (kk < KCPI) {
                const int kc = i * KCPI + kk;
                const unsigned short* pa = Arow0 + (size_t)kc * 4096;
                bf16x8 A0 = *(const bf16x8*)pa;
                bf16x8 A1 = *(const bf16x8*)(pa + 512);
                bf16x8 B0 = *(const bf16x8*)&Bp[(0 * KCPI + kk) * 512 + lane * 8];
                bf16x8 B1 = *(const bf16x8*)&Bp[(1 * KCPI + kk) * 512 + lane * 8];
                acc[0][0] = __builtin_amdgcn_mfma_f32_32x32x16_bf16(A0, B0, acc[0][0], 0, 0, 0);
                acc[0][1] = __builtin_amdgcn_mfma_f32_32x32x16_bf16(A0, B1, acc[0][1], 0, 0, 0);
                acc[1][0] = __builtin_amdgcn_mfma_f32_32x32x16_bf16(A1, B0, acc[1][0], 0, 0, 0);
                acc[1][1] = __builtin_amdgcn_mfma_f32_32x32x16_bf16(A1, B1, acc[1][1], 0, 0, 0);
            }
        }
        __syncthreads();   // protect Bp before next build
    }

    // combine k-halves via LDS (HtS/Bp dead), then store
    float* cb = (float*)SM;   // 32 KB scratch
#pragma unroll 1
    for (int r = 0; r < 2; ++r) {
        __syncthreads();
        if (kh == 1 && (tg >> 1) == r) {
            int s = tg & 1;
#pragma unroll
            for (int ta = 0; ta < 2; ++ta)
#pragma unroll
                for (int bb = 0; bb < 2; ++bb)
#pragma unroll
                    for (int reg = 0; reg < 16; ++reg)
                        cb[((((s * 2 + ta) * 2 + bb) * 16) + reg) * 64 + lane] =
                            acc[ta][bb][reg];
        }
        __syncthreads();
        if (kh == 0 && (tg >> 1) == r) {
            int s = tg & 1;
#pragma unroll
            for (int ta = 0; ta < 2; ++ta) {
                int tile = 2 * tg + ta;
                if (tile < 7) {
#pragma unroll
                    for (int bb = 0; bb < 2; ++bb) {
                        unsigned short* dst =
                            Hout + ((size_t)(b0 + bb) * CIN_D + l32) * 224;
#pragma unroll
                        for (int qd = 0; qd < 4; ++qd) {
                            int n0 = tile * 32 + 8 * qd + 4 * hl;
                            ushort4 pk;
                            pk.x = f2b(acc[ta][bb][4 * qd + 0] +
                                       cb[((((s * 2 + ta) * 2 + bb) * 16) + 4 * qd + 0) * 64 + lane]);
                            pk.y = f2b(acc[ta][bb][4 * qd + 1] +
                                       cb[((((s * 2 + ta) * 2 + bb) * 16) + 4 * qd + 1) * 64 + lane]);
                            pk.z = f2b(acc[ta][bb][4 * qd + 2] +
                                       cb[((((s * 2 + ta) * 2 + bb) * 16) + 4 * qd + 2) * 64 + lane]);
                            pk.w = f2b(acc[ta][bb][4 * qd + 3] +
                                       cb[((((s * 2 + ta) * 2 + bb) * 16) + 4 * qd + 3) * 64 + lane]);
                            *(ushort4*)&dst[n0] = pk;
                        }
                    }
                }
            }
        }
    }
}

// out[b, l*200+n] = sum_d H_l[b][d][n]
__global__ __launch_bounds__(256) void cin_reduce(const unsigned short* __restrict__ H1,
                                                  const unsigned short* __restrict__ H2,
                                                  const unsigned short* __restrict__ H3,
                                                  float* __restrict__ out) {
    __shared__ __align__(16) unsigned short L[CIN_D][224];
    const int bid = blockIdx.x;            // 0..1535
    const int b = bid / 3, l = bid % 3;
    const unsigned short* H = (l == 0 ? H1 : (l == 1 ? H2 : H3)) + (size_t)b * CIN_D * 224;
    const uint4* src = (const uint4*)H;
    for (int g = threadIdx.x; g < CIN_D * 224 / 8; g += 256) {
        int r = g / 28, c = g - r * 28;
        *(uint4*)&L[r][c * 8] = src[g];
    }
    __syncthreads();
    int n = threadIdx.x;
    if (n < CIN_S) {
        float s = 0.f;
#pragma unroll
        for (int dd = 0; dd < CIN_D; ++dd) s += b2f(L[dd][n]);
        out[(size_t)b * (3 * CIN_S) + l * CIN_S + n] = s;
    }
}

extern "C" void kernel_launch(void* const* d_in, const int* in_sizes, int n_in,
                              void* d_out, int out_size, void* d_ws, size_t ws_size,
                              hipStream_t stream) {
    const float* X  = (const float*)d_in[0];
    const float* W0 = (const float*)d_in[1];
    const float* W1 = (const float*)d_in[2];
    const float* W2 = (const float*)d_in[3];
    float* out = (float*)d_out;

    unsigned short* Wtk1 = (unsigned short*)d_ws;            // 120*256*16
    unsigned short* Wtk2 = Wtk1 + (size_t)120 * 4096;        // 560*256*16
    unsigned short* Wtk3 = Wtk2 + (size_t)560 * 4096;
    unsigned short* X0h  = Wtk3 + (size_t)560 * 4096;        // 512*32*48
    unsigned short* H1   = X0h + (size_t)CIN_B * CIN_D * 48; // 512*32*224 each
    unsigned short* H2   = H1 + (size_t)CIN_B * CIN_D * 224;
    unsigned short* H3   = H2 + (size_t)CIN_B * CIN_D * 224;
    float* Xs = (float*)(H3 + (size_t)CIN_B * CIN_D * 224);  // 512*40*32 fp32
    // total ws ~36.4 MB

    prep_w<CIN_F0, 3><<<120, 256, 0, stream>>>(W0, Wtk1);
    prep_w<CIN_S, 14><<<560, 256, 0, stream>>>(W1, Wtk2);
    prep_w<CIN_S, 14><<<560, 256, 0, stream>>>(W2, Wtk3);
    prep_x<<<(CIN_B * CIN_F0 * CIN_D) / 256, 256, 0, stream>>>(X, X0h, Xs);

    cin_layer<3, 56, 48><<<CIN_B / 2, 512, 0, stream>>>(X0h, Xs, Wtk1, H1);
    cin_layer<14, 232, 224><<<CIN_B / 2, 512, 0, stream>>>(H1, Xs, Wtk2, H2);
    cin_layer<14, 232, 224><<<CIN_B / 2, 512, 0, stream>>>(H2, Xs, Wtk3, H3);

    cin_reduce<<<CIN_B * 3, 256, 0, stream>>>(H1, H2, H3, out);
}

// Round 5
// 305.110 us; speedup vs baseline: 14.3713x; 1.2026x over previous
//
#include <hip/hip_runtime.h>

#define CIN_B 512
#define CIN_F0 40
#define CIN_D 32
#define CIN_S 200

typedef short bf16x8 __attribute__((ext_vector_type(8)));
typedef float floatx16 __attribute__((ext_vector_type(16)));

__device__ __forceinline__ float bits2f(unsigned int u) {
    union { unsigned int i; float f; } c; c.i = u; return c.f;
}
__device__ __forceinline__ unsigned short f2b(float f) {
    union { float f; unsigned int i; } c; c.f = f;
    unsigned int i = c.i;
    return (unsigned short)((i + 0x7fffu + ((i >> 16) & 1u)) >> 16);  // RNE
}
__device__ __forceinline__ float b2f(unsigned short u) {
    return bits2f(((unsigned int)u) << 16);
}

// Wtk[kc][nn 0..255][kw 0..15] = bf16(W[(i*FI + kk*16+kw)*200 + nn]); kc = i*KCPI+kk.
// Zero-pad nn>=200 and j>=FI. One block per kc; coalesced W reads (nn = lane).
template <int FI, int KCPI>
__global__ __launch_bounds__(256) void prep_w(const float* __restrict__ W,
                                              unsigned short* __restrict__ Wtk) {
    const int kc = blockIdx.x;
    const int nn = threadIdx.x;
    const int i = kc / KCPI;
    const int kk = kc - i * KCPI;
    unsigned short v[16];
#pragma unroll
    for (int kw = 0; kw < 16; ++kw) {
        int j = kk * 16 + kw;
        float f = 0.f;
        if (j < FI && nn < CIN_S) f = W[(size_t)(i * FI + j) * CIN_S + nn];
        v[kw] = f2b(f);
    }
    uint4* dst = (uint4*)(Wtk + ((size_t)kc * 256 + nn) * 16);
    dst[0] = ((const uint4*)v)[0];
    dst[1] = ((const uint4*)v)[1];
}

// X0h[b][d][i(pad 48)] = bf16(x0[b][i][d]);  Xs[b][i][d] = fp32 x0.
__global__ __launch_bounds__(256) void prep_x(const float* __restrict__ X,
                                              unsigned short* __restrict__ X0h,
                                              float* __restrict__ Xs) {
    int e = blockIdx.x * 256 + threadIdx.x;   // 512*40*32
    int d = e & 31;
    int rest = e >> 5;
    int i = rest % CIN_F0;
    int b = rest / CIN_F0;
    float v = X[e];
    Xs[e] = v;
    X0h[((size_t)b * CIN_D + d) * 48 + i] = f2b(v);
    if (e < CIN_B * CIN_D * 8) {     // zero pads i=40..47
        int q = e & 7, dd = (e >> 3) & 31, bb = e >> 8;
        X0h[((size_t)bb * CIN_D + dd) * 48 + 40 + q] = 0;
    }
}

// Layer: Hout[b][d][n] = sum_i x0[b][i][d] * (sum_j Wt[n,(i,j)] * h[b][j][d])
// Grid: 512 blocks (1 per b) x 8 waves; wave = one 32-row n-tile, full K.
// B-frags (h only, i-invariant) live in VGPRs for the whole kernel: no LDS,
// no barriers. A streamed from global (Wtk k-major, coalesced 16B/lane).
// mfma_f32_32x32x16_bf16: A[m=lane&31][k=(lane>>5)*8+e] (m = n-row);
// B[k][col=lane&31] (col = d); C/D col=lane&31, row=(reg&3)+8*(reg>>2)+4*(lane>>5).
template <int KCPI, int JROW>
__global__ __launch_bounds__(512, 4)
void cin_layer(const unsigned short* __restrict__ Hin,   // [b][32][JROW] bf16
               const float* __restrict__ Xs,             // [b][40][32] fp32
               const unsigned short* __restrict__ Wtk,   // [kc][256][16] bf16
               unsigned short* __restrict__ Hout) {      // [b][32][224] bf16
    const int b = blockIdx.x;
    const int wave = threadIdx.x >> 6;
    if (wave == 7) return;            // tile 7 = zero-pad rows 224..255
    const int lane = threadIdx.x & 63;
    const int l32 = lane & 31, hl = lane >> 5;
    const int tile = wave;            // n-rows tile*32 .. tile*32+31

    // B-frags: Bf[kk] lane holds h[d=l32][j = kk*16 + hl*8 + e], e=0..7
    bf16x8 Bf[KCPI];
    {
        const unsigned short* hrow = Hin + ((size_t)b * CIN_D + l32) * JROW + hl * 8;
#pragma unroll
        for (int kk = 0; kk < KCPI; ++kk)
            Bf[kk] = *(const bf16x8*)(hrow + kk * 16);
    }

    const unsigned short* Abase = Wtk + ((size_t)(tile * 32 + l32) * 16 + hl * 8);
    const float* xsb = Xs + (size_t)b * (CIN_F0 * CIN_D) + l32;

    floatx16 acc;
#pragma unroll
    for (int r = 0; r < 16; ++r) acc[r] = 0.f;
    floatx16 z16;
#pragma unroll
    for (int r = 0; r < 16; ++r) z16[r] = 0.f;

#pragma unroll 1
    for (int i = 0; i < CIN_F0; ++i) {
        const float xf = xsb[(size_t)i * CIN_D];
        floatx16 P;
#pragma unroll
        for (int kk = 0; kk < KCPI; ++kk) {
            const bf16x8 Af =
                *(const bf16x8*)(Abase + (size_t)(i * KCPI + kk) * 4096);
            P = __builtin_amdgcn_mfma_f32_32x32x16_bf16(Af, Bf[kk],
                                                        (kk == 0) ? z16 : P, 0, 0, 0);
        }
#pragma unroll
        for (int r = 0; r < 16; ++r) acc[r] += xf * P[r];
    }

    // epilogue: C[n][d] -> Hout[b][d][n]; rows = (reg&3)+8*qd+4*hl, col = l32
    unsigned short* dst = Hout + ((size_t)b * CIN_D + l32) * 224 + tile * 32;
#pragma unroll
    for (int qd = 0; qd < 4; ++qd) {
        ushort4 pk;
        pk.x = f2b(acc[4 * qd + 0]);
        pk.y = f2b(acc[4 * qd + 1]);
        pk.z = f2b(acc[4 * qd + 2]);
        pk.w = f2b(acc[4 * qd + 3]);
        *(ushort4*)&dst[8 * qd + 4 * hl] = pk;
    }
}

// out[b, l*200+n] = sum_d H_l[b][d][n]
__global__ __launch_bounds__(256) void cin_reduce(const unsigned short* __restrict__ H1,
                                                  const unsigned short* __restrict__ H2,
                                                  const unsigned short* __restrict__ H3,
                                                  float* __restrict__ out) {
    __shared__ __align__(16) unsigned short L[CIN_D][224];
    const int bid = blockIdx.x;            // 0..1535
    const int b = bid / 3, l = bid % 3;
    const unsigned short* H = (l == 0 ? H1 : (l == 1 ? H2 : H3)) + (size_t)b * CIN_D * 224;
    const uint4* src = (const uint4*)H;
    for (int g = threadIdx.x; g < CIN_D * 224 / 8; g += 256) {
        int r = g / 28, c = g - r * 28;
        *(uint4*)&L[r][c * 8] = src[g];
    }
    __syncthreads();
    int n = threadIdx.x;
    if (n < CIN_S) {
        float s = 0.f;
#pragma unroll
        for (int dd = 0; dd < CIN_D; ++dd) s += b2f(L[dd][n]);
        out[(size_t)b * (3 * CIN_S) + l * CIN_S + n] = s;
    }
}

extern "C" void kernel_launch(void* const* d_in, const int* in_sizes, int n_in,
                              void* d_out, int out_size, void* d_ws, size_t ws_size,
                              hipStream_t stream) {
    const float* X  = (const float*)d_in[0];
    const float* W0 = (const float*)d_in[1];
    const float* W1 = (const float*)d_in[2];
    const float* W2 = (const float*)d_in[3];
    float* out = (float*)d_out;

    unsigned short* Wtk1 = (unsigned short*)d_ws;            // 120*256*16
    unsigned short* Wtk2 = Wtk1 + (size_t)120 * 4096;        // 560*256*16
    unsigned short* Wtk3 = Wtk2 + (size_t)560 * 4096;
    unsigned short* X0h  = Wtk3 + (size_t)560 * 4096;        // 512*32*48
    unsigned short* H1   = X0h + (size_t)CIN_B * CIN_D * 48; // 512*32*224 each
    unsigned short* H2   = H1 + (size_t)CIN_B * CIN_D * 224;
    unsigned short* H3   = H2 + (size_t)CIN_B * CIN_D * 224;
    float* Xs = (float*)(H3 + (size_t)CIN_B * CIN_D * 224);  // 512*40*32 fp32
    // total ws ~36.4 MB

    prep_w<CIN_F0, 3><<<120, 256, 0, stream>>>(W0, Wtk1);
    prep_w<CIN_S, 14><<<560, 256, 0, stream>>>(W1, Wtk2);
    prep_w<CIN_S, 14><<<560, 256, 0, stream>>>(W2, Wtk3);
    prep_x<<<(CIN_B * CIN_F0 * CIN_D) / 256, 256, 0, stream>>>(X, X0h, Xs);

    cin_layer<3, 48><<<CIN_B, 512, 0, stream>>>(X0h, Xs, Wtk1, H1);
    cin_layer<14, 224><<<CIN_B, 512, 0, stream>>>(H1, Xs, Wtk2, H2);
    cin_layer<14, 224><<<CIN_B, 512, 0, stream>>>(H2, Xs, Wtk3, H3);

    cin_reduce<<<CIN_B * 3, 256, 0, stream>>>(H1, H2, H3, out);
}